// Round 7
// baseline (92.273 us; speedup 1.0000x reference)
//
#include <hip/hip_runtime.h>
#include <hip/hip_fp16.h>

#define BB 16
#define HH 512
#define WW 512
#define NVV 35709
#define NTT 70000
#define HWW (HH * WW)

// World model (R0-R5):
//   proj_geo, texture, nbl, ori_img : float32
//   is_visible, tri_inds, pixel_valid : int32
//   OUTPUT: float32, concatenated [render BHW3 | real BHW3]
//
// Accumulator (d_ws): __half2 acc[B*HW*2]; per pixel: [0]=(r,g), [1]=(b,w).
// 8 B/pixel -> halves zero + compose-read traffic vs f32. f16 accumulation
// error after /w is ~1e-3 (per-pixel counts tiny, lambda~0.09), threshold 2e-2.

typedef float fvec4 __attribute__((ext_vector_type(4)));   // native vector for
                                                           // nontemporal stores

__global__ __launch_bounds__(256) void zero_kernel(float4* __restrict__ p, long n4)
{
    long i = (long)blockIdx.x * blockDim.x + threadIdx.x;
    long stride = (long)gridDim.x * blockDim.x;
    float4 z = {0.f, 0.f, 0.f, 0.f};
    for (; i < n4; i += stride) p[i] = z;
}

__device__ inline void pk_add(__half2* p, __half2 v)
{
    unsafeAtomicAdd(p, v);   // global_atomic_pk_add_f16 on gfx950
}

__global__ __launch_bounds__(256) void splat_kernel(
    const float* __restrict__ proj,
    const float* __restrict__ tex,
    const float* __restrict__ nbl,
    const int* __restrict__ vis,
    const int* __restrict__ tri,
    __half2* __restrict__ acc,
    int b0)
{
    int t = blockIdx.x * blockDim.x + threadIdx.x;
    if (t >= NTT) return;
    int bl = blockIdx.y;          // local batch index within this pass
    int b = b0 + bl;              // global batch

    int i0 = tri[t * 3 + 0];
    int i1 = tri[t * 3 + 1];
    int i2 = tri[t * 3 + 2];

    int base = b * NVV;
    // tri_w = min(vis) over {0,1}; zero-weight triangles contribute nothing.
    if (vis[base + i0] == 0 || vis[base + i1] == 0 || vis[base + i2] == 0) return;

    long p0 = (long)(base + i0) * 3;
    long p1 = (long)(base + i1) * 3;
    long p2 = (long)(base + i2) * 3;

    float x0 = proj[p0 + 0], y0 = proj[p0 + 1];
    float x1 = proj[p1 + 0], y1 = proj[p1 + 1];
    float x2 = proj[p2 + 0], y2 = proj[p2 + 1];

    float fx = ((x0 + x1) + x2) / 3.0f;   // numpy f32 pairwise sum + true_divide
    float fy = ((y0 + y1) + y2) / 3.0f;

    int px = (int)rintf(fx);              // np.round = round-half-even
    int py = (int)rintf(fy);
    px = min(max(px, 0), WW - 1);
    py = min(max(py, 0), HH - 1);

    float c0r = tex[p0 + 0] * nbl[p0 + 0];
    float c0g = tex[p0 + 1] * nbl[p0 + 1];
    float c0b = tex[p0 + 2] * nbl[p0 + 2];
    float c1r = tex[p1 + 0] * nbl[p1 + 0];
    float c1g = tex[p1 + 1] * nbl[p1 + 1];
    float c1b = tex[p1 + 2] * nbl[p1 + 2];
    float c2r = tex[p2 + 0] * nbl[p2 + 0];
    float c2g = tex[p2 + 1] * nbl[p2 + 1];
    float c2b = tex[p2 + 2] * nbl[p2 + 2];

    float cr = ((c0r + c1r) + c2r) / 3.0f;
    float cg = ((c0g + c1g) + c2g) / 3.0f;
    float cb = ((c0b + c1b) + c2b) / 3.0f;

    long lin = (long)bl * HWW + (long)py * WW + px;   // LOCAL accumulator index
    pk_add(&acc[lin * 2 + 0], __floats2half2_rn(cr, cg));
    pk_add(&acc[lin * 2 + 1], __floats2half2_rn(cb, 1.0f));
}

__device__ inline float2 unpack_h2(float w)
{
    __half2 h = __builtin_bit_cast(__half2, w);
    return make_float2(__low2float(h), __high2float(h));
}

// 4 pixels per thread, all loads/stores 16B vectors.
__global__ __launch_bounds__(256) void compose_kernel(
    const float4* __restrict__ accv,     // local (pass) accumulator as float4
    const float4* __restrict__ oriv,
    const int4* __restrict__ pvv,
    fvec4* __restrict__ outv,
    int b0, int nb)
{
    long q = (long)blockIdx.x * blockDim.x + threadIdx.x;   // local 4-pixel group
    long ngrp = (long)nb * (HWW / 4);
    if (q >= ngrp) return;
    long qg = (long)b0 * (HWW / 4) + q;                     // global group

    float4 A0 = accv[q * 2 + 0];   // pixels 0,1: (rg,bw),(rg,bw)
    float4 A1 = accv[q * 2 + 1];   // pixels 2,3
    int4 PV = pvv[qg];
    float4 O0 = oriv[qg * 3 + 0];
    float4 O1 = oriv[qg * 3 + 1];
    float4 O2 = oriv[qg * 3 + 2];

    float of[12] = {O0.x, O0.y, O0.z, O0.w, O1.x, O1.y, O1.z, O1.w,
                    O2.x, O2.y, O2.z, O2.w};
    float2 rg[4], bw[4];
    rg[0] = unpack_h2(A0.x); bw[0] = unpack_h2(A0.y);
    rg[1] = unpack_h2(A0.z); bw[1] = unpack_h2(A0.w);
    rg[2] = unpack_h2(A1.x); bw[2] = unpack_h2(A1.y);
    rg[3] = unpack_h2(A1.z); bw[3] = unpack_h2(A1.w);
    int pva[4] = {PV.x, PV.y, PV.z, PV.w};

    float rd[12], rl[12];
#pragma unroll
    for (int p = 0; p < 4; ++p) {
        float w = bw[p].y;
        bool pv = pva[p] > 0;
        bool cov = (w > 0.f) && pv;
        float dn = fmaxf(w, 1.f);
        float fr = rg[p].x / dn;
        float fg = rg[p].y / dn;
        float fb = bw[p].x / dn;
        rd[p * 3 + 0] = cov ? fr : of[p * 3 + 0];
        rd[p * 3 + 1] = cov ? fg : of[p * 3 + 1];
        rd[p * 3 + 2] = cov ? fb : of[p * 3 + 2];
        rl[p * 3 + 0] = pv ? of[p * 3 + 0] : 0.f;
        rl[p * 3 + 1] = pv ? of[p * 3 + 1] : 0.f;
        rl[p * 3 + 2] = pv ? of[p * 3 + 2] : 0.f;
    }

    const long RO4 = (long)BB * HWW * 3 / 4;   // `real` offset in float4 units
    fvec4 R0 = {rd[0], rd[1], rd[2], rd[3]};
    fvec4 R1 = {rd[4], rd[5], rd[6], rd[7]};
    fvec4 R2 = {rd[8], rd[9], rd[10], rd[11]};
    fvec4 L0 = {rl[0], rl[1], rl[2], rl[3]};
    fvec4 L1 = {rl[4], rl[5], rl[6], rl[7]};
    fvec4 L2 = {rl[8], rl[9], rl[10], rl[11]};
    __builtin_nontemporal_store(R0, &outv[qg * 3 + 0]);
    __builtin_nontemporal_store(R1, &outv[qg * 3 + 1]);
    __builtin_nontemporal_store(R2, &outv[qg * 3 + 2]);
    __builtin_nontemporal_store(L0, &outv[RO4 + qg * 3 + 0]);
    __builtin_nontemporal_store(L1, &outv[RO4 + qg * 3 + 1]);
    __builtin_nontemporal_store(L2, &outv[RO4 + qg * 3 + 2]);
}

extern "C" void kernel_launch(void* const* d_in, const int* in_sizes, int n_in,
                              void* d_out, int out_size, void* d_ws, size_t ws_size,
                              hipStream_t stream) {
    const float* proj = (const float*)d_in[0];
    const float* tex  = (const float*)d_in[1];
    const float* nbl  = (const float*)d_in[2];
    const float* ori  = (const float*)d_in[3];
    const int* vis    = (const int*)d_in[4];
    const int* tri    = (const int*)d_in[5];
    const int* pvalid = (const int*)d_in[6];
    float* out        = (float*)d_out;

    // 8 bytes per pixel accumulator.
    const size_t perBatchBytes = (size_t)HWW * 8;
    int nbMax = (int)(ws_size / perBatchBytes);
    if (nbMax < 1) nbMax = 1;
    if (nbMax > BB) nbMax = BB;

    for (int b0 = 0; b0 < BB; b0 += nbMax) {
        int nb = (BB - b0 < nbMax) ? (BB - b0) : nbMax;

        __half2* acc = (__half2*)d_ws;                     // nb*HW*2 half2

        long n4 = (long)nb * HWW / 2;                      // float4 count (8B/px)
        int zblocks = (int)((n4 + 255) / 256);
        if (zblocks > 4096) zblocks = 4096;
        zero_kernel<<<zblocks, 256, 0, stream>>>((float4*)d_ws, n4);

        dim3 gs((NTT + 255) / 256, nb);
        splat_kernel<<<gs, 256, 0, stream>>>(proj, tex, nbl, vis, tri, acc, b0);

        long ngrp = (long)nb * (HWW / 4);
        compose_kernel<<<(int)((ngrp + 255) / 256), 256, 0, stream>>>(
            (const float4*)d_ws, (const float4*)ori, (const int4*)pvalid,
            (fvec4*)out, b0, nb);
    }
}